// Round 3
// baseline (146.808 us; speedup 1.0000x reference)
//
#include <hip/hip_runtime.h>
#include <stdint.h>

// MLA attention, MI355X round 3.
// Stage 1: kv = compressed_kv @ w_up^T  (bf16 MFMA, m97-style 128x128 tile)
// Stage 2: causal flash attention, bf16 MFMA. Round-3: CU-level causal load
//          balancing (qt remap), K/V fragment reuse across m-halves, T14
//          reg-staged prefetch of next KV tile, rope pre-converted to bf16.

#define Bz 4
#define Sz 1024
#define Hz 16
#define RANKz 512
#define SCALEf 0.07216878364870323f

typedef __attribute__((ext_vector_type(8))) short bf16x8;
typedef __attribute__((ext_vector_type(4))) float f32x4;

__device__ __forceinline__ unsigned short f2b(float f) {
  union { float f; uint32_t u; } x; x.f = f;
  return (unsigned short)((x.u + 0x7fffu + ((x.u >> 16) & 1u)) >> 16);
}

// ---------------------------------------------------------------- cvt fp32->bf16
// a: ckv (na float4), b: w_up (nb float4), c: rope (rest)
__global__ void cvt_bf16_kernel(const float* __restrict__ a, unsigned short* __restrict__ ao,
                                const float* __restrict__ b, unsigned short* __restrict__ bo,
                                const float* __restrict__ c, unsigned short* __restrict__ co,
                                int na, int nb) {
  int idx = blockIdx.x * blockDim.x + threadIdx.x;
  const float* s; unsigned short* d; int i;
  if (idx < na)            { s = a; d = ao; i = idx; }
  else if (idx < na + nb)  { s = b; d = bo; i = idx - na; }
  else                     { s = c; d = co; i = idx - na - nb; }
  float4 v = ((const float4*)s)[i];
  ushort4 o = make_ushort4(f2b(v.x), f2b(v.y), f2b(v.z), f2b(v.w));
  ((ushort4*)d)[i] = o;
}

// ---------------------------------------------------------------- stage 1 GEMM
__global__ __launch_bounds__(256)
void gemm_kv_bf16(const unsigned short* __restrict__ A,
                  const unsigned short* __restrict__ Bm,
                  unsigned short* __restrict__ C) {
  __shared__ unsigned short As[128 * 32];
  __shared__ unsigned short Bs[128 * 32];
  const int tid = threadIdx.x;
  const int w = tid >> 6, lane = tid & 63;
  const int wr = w >> 1, wc = w & 1;
  const int row0 = blockIdx.x * 128, col0 = blockIdx.y * 128;
  f32x4 acc[4][4];
#pragma unroll
  for (int m = 0; m < 4; ++m)
#pragma unroll
    for (int n = 0; n < 4; ++n) acc[m][n] = (f32x4){0.f, 0.f, 0.f, 0.f};

  const int rstage = (lane >> 2);
  const int cstage = (lane & 3) * 8;

  for (int kt = 0; kt < RANKz / 32; ++kt) {
    const int k0 = kt * 32;
#pragma unroll
    for (int i = 0; i < 2; ++i) {
      const int chunk = i * 4 + w;
      const int r = chunk * 16 + rstage;
      const unsigned short* ga = A  + (size_t)(row0 + r) * RANKz + k0 + cstage;
      const unsigned short* gb = Bm + (size_t)(col0 + r) * RANKz + k0 + cstage;
      __builtin_amdgcn_global_load_lds((const __attribute__((address_space(1))) void*)ga,
                                       (__attribute__((address_space(3))) void*)&As[chunk * 512], 16, 0, 0);
      __builtin_amdgcn_global_load_lds((const __attribute__((address_space(1))) void*)gb,
                                       (__attribute__((address_space(3))) void*)&Bs[chunk * 512], 16, 0, 0);
    }
    __syncthreads();
    const int klo = (lane >> 4) * 8;
    bf16x8 af[4], bfr[4];
#pragma unroll
    for (int m = 0; m < 4; ++m)
      af[m] = *(const bf16x8*)&As[(wr * 64 + m * 16 + (lane & 15)) * 32 + klo];
#pragma unroll
    for (int n = 0; n < 4; ++n)
      bfr[n] = *(const bf16x8*)&Bs[(wc * 64 + n * 16 + (lane & 15)) * 32 + klo];
#pragma unroll
    for (int m = 0; m < 4; ++m)
#pragma unroll
      for (int n = 0; n < 4; ++n)
        acc[m][n] = __builtin_amdgcn_mfma_f32_16x16x32_bf16(af[m], bfr[n], acc[m][n], 0, 0, 0);
    __syncthreads();
  }
  const int cb = col0 + wc * 64 + (lane & 15);
  const int rb = row0 + wr * 64 + (lane >> 4) * 4;
#pragma unroll
  for (int m = 0; m < 4; ++m)
#pragma unroll
    for (int n = 0; n < 4; ++n)
#pragma unroll
      for (int j = 0; j < 4; ++j)
        C[(size_t)(rb + m * 16 + j) * 4096 + (cb + n * 16)] = f2b(acc[m][n][j]);
}

// ---------------------------------------------------------------- stage 2 helpers
struct Pref { uint4 kr[4]; uint4 rr[2]; uint4 vr[4]; };

__device__ __forceinline__ void load_tile(Pref& P, const unsigned short* __restrict__ kvp,
                                          const unsigned short* __restrict__ rp, int tid) {
#pragma unroll
  for (int i = 0; i < 4; ++i) {
    const int task = tid + i * 256, r = task >> 4, c = task & 15;
    P.kr[i] = *(const uint4*)&kvp[(size_t)r * 4096 + c * 8];
  }
#pragma unroll
  for (int i = 0; i < 2; ++i) {
    const int task = tid + i * 256, r = task >> 3, c = task & 7;
    P.rr[i] = *(const uint4*)&rp[(size_t)r * 64 + c * 8];
  }
#pragma unroll
  for (int i = 0; i < 2; ++i) {
    const int task = tid + i * 256, kp = task & 31, dc = task >> 5;
    P.vr[2 * i]     = *(const uint4*)&kvp[(size_t)(kp * 2) * 4096 + 128 + dc * 8];
    P.vr[2 * i + 1] = *(const uint4*)&kvp[(size_t)(kp * 2 + 1) * 4096 + 128 + dc * 8];
  }
}

__device__ __forceinline__ void write_tile(const Pref& P, unsigned short (*Ks)[200],
                                           unsigned short (*Vt)[72], int tid) {
#pragma unroll
  for (int i = 0; i < 4; ++i) {
    const int task = tid + i * 256, r = task >> 4, c = task & 15;
    *(uint4*)&Ks[r][c * 8] = P.kr[i];
  }
#pragma unroll
  for (int i = 0; i < 2; ++i) {
    const int task = tid + i * 256, r = task >> 3, c = task & 7;
    *(uint4*)&Ks[r][128 + c * 8] = P.rr[i];
  }
#pragma unroll
  for (int i = 0; i < 2; ++i) {
    const int task = tid + i * 256, kp = task & 31, dc = task >> 5;
    const int k0 = kp * 2, d0 = dc * 8;
    union { uint4 v; unsigned short u[8]; } a_, b_;
    a_.v = P.vr[2 * i]; b_.v = P.vr[2 * i + 1];
#pragma unroll
    for (int jj = 0; jj < 8; ++jj) {
      const uint32_t pk = (uint32_t)a_.u[jj] | ((uint32_t)b_.u[jj] << 16);
      *(uint32_t*)&Vt[d0 + jj][k0] = pk;
    }
  }
}

// ---------------------------------------------------------------- stage 2: MFMA attention
// grid (8, 64), 256 thr = 4 waves; wave owns 32 q-rows (2 m-halves of 16); KV tile 64.
// qt remapped so block pairs (idx, idx+256) on one CU get qt and 7-qt (causal balance).
__global__ __launch_bounds__(256, 2)
void mla_attn_mfma(const float* __restrict__ q,
                   const unsigned short* __restrict__ kvb,   // [T][16*256] bf16
                   const unsigned short* __restrict__ ropeb, // [T][64] bf16
                   float* __restrict__ out) {                // [T][16][128] fp32
  __shared__ unsigned short Ks[64][200];   // K tile (128 nope + 64 rope)
  __shared__ unsigned short Vt[128][72];   // V transposed [d][k]
  __shared__ unsigned short Ps[4][32][72]; // per-wave P (rows 0-15 mh0, 16-31 mh1)

  const int tid = threadIdx.x;
  const int w = tid >> 6, lane = tid & 63;
  const int lr = lane & 15, lg = lane >> 4;
  const int bh = blockIdx.y;
  const int qt = (bh >= 32) ? (7 - (int)blockIdx.x) : (int)blockIdx.x;
  const int bat = bh >> 4, h = bh & 15;
  const int qbase = qt * 128;
  const int row0 = qbase + w * 32;         // wave's first q-row (mh0: +0..15, mh1: +16..31)

  // ---- Q fragments, prescaled by SCALE, bf16, in registers
  bf16x8 qf[2][6];
#pragma unroll
  for (int mh = 0; mh < 2; ++mh) {
    const int qrow = row0 + mh * 16 + lr;
    const float* qp = q + ((size_t)(bat * Sz + qrow) * Hz + h) * 192 + lg * 8;
#pragma unroll
    for (int ks = 0; ks < 6; ++ks) {
      float4 a = *(const float4*)(qp + ks * 32);
      float4 b = *(const float4*)(qp + ks * 32 + 4);
      union { bf16x8 v; unsigned short u[8]; } t;
      t.u[0] = f2b(a.x * SCALEf); t.u[1] = f2b(a.y * SCALEf);
      t.u[2] = f2b(a.z * SCALEf); t.u[3] = f2b(a.w * SCALEf);
      t.u[4] = f2b(b.x * SCALEf); t.u[5] = f2b(b.y * SCALEf);
      t.u[6] = f2b(b.z * SCALEf); t.u[7] = f2b(b.w * SCALEf);
      qf[mh][ks] = t.v;
    }
  }

  f32x4 acc[2][8];
#pragma unroll
  for (int mh = 0; mh < 2; ++mh)
#pragma unroll
    for (int n = 0; n < 8; ++n) acc[mh][n] = (f32x4){0.f, 0.f, 0.f, 0.f};
  float m_run[2][4], l_run[2][4];
#pragma unroll
  for (int mh = 0; mh < 2; ++mh)
#pragma unroll
    for (int j = 0; j < 4; ++j) { m_run[mh][j] = -1e30f; l_run[mh][j] = 0.f; }

  const int ntiles = 2 * qt + 2;
  Pref P;

  // prologue: stage tile 0
  {
    const unsigned short* kvp = kvb + ((size_t)(bat * Sz) * Hz + h) * 256;
    const unsigned short* rp  = ropeb + (size_t)(bat * Sz) * 64;
    load_tile(P, kvp, rp, tid);
    write_tile(P, Ks, Vt, tid);
  }
  __syncthreads();

  for (int t = 0; t < ntiles; ++t) {
    const int ks0 = t * 64;
    // ---- issue next tile's global loads (overlap with compute below)
    {
      const int tn = (t + 1 < ntiles) ? t + 1 : t;
      const unsigned short* kvp = kvb + ((size_t)(bat * Sz + tn * 64) * Hz + h) * 256;
      const unsigned short* rp  = ropeb + (size_t)(bat * Sz + tn * 64) * 64;
      load_tile(P, kvp, rp, tid);
    }

    if (ks0 <= row0 + 31) {   // wave-active (mh1 still has unmasked rows)
      // ---- QK^T, K fragments shared across both m-halves
      f32x4 sfr[2][4];
#pragma unroll
      for (int mh = 0; mh < 2; ++mh)
#pragma unroll
        for (int n = 0; n < 4; ++n) sfr[mh][n] = (f32x4){0.f, 0.f, 0.f, 0.f};
#pragma unroll
      for (int ks = 0; ks < 6; ++ks)
#pragma unroll
        for (int n = 0; n < 4; ++n) {
          bf16x8 bk = *(const bf16x8*)&Ks[n * 16 + lr][ks * 32 + lg * 8];
          sfr[0][n] = __builtin_amdgcn_mfma_f32_16x16x32_bf16(qf[0][ks], bk, sfr[0][n], 0, 0, 0);
          sfr[1][n] = __builtin_amdgcn_mfma_f32_16x16x32_bf16(qf[1][ks], bk, sfr[1][n], 0, 0, 0);
        }

      // ---- per m-half: mask + online softmax + P write
#pragma unroll
      for (int mh = 0; mh < 2; ++mh) {
        const int row_m = row0 + mh * 16;
        const bool edge = (ks0 + 63 > row_m);
        float sv[4][4];
#pragma unroll
        for (int n = 0; n < 4; ++n)
#pragma unroll
          for (int j = 0; j < 4; ++j) {
            float s = sfr[mh][n][j];
            if (edge && (ks0 + n * 16 + lr > row_m + lg * 4 + j)) s = -1e30f;
            sv[n][j] = s;
          }
        float mxj[4];
#pragma unroll
        for (int j = 0; j < 4; ++j)
          mxj[j] = fmaxf(fmaxf(sv[0][j], sv[1][j]), fmaxf(sv[2][j], sv[3][j]));
#pragma unroll
        for (int off = 1; off < 16; off <<= 1)
#pragma unroll
          for (int j = 0; j < 4; ++j) mxj[j] = fmaxf(mxj[j], __shfl_xor(mxj[j], off));

        float nm[4], cr[4];
#pragma unroll
        for (int j = 0; j < 4; ++j) {
          nm[j] = fmaxf(m_run[mh][j], mxj[j]);
          cr[j] = __expf(m_run[mh][j] - nm[j]);
          m_run[mh][j] = nm[j];
        }
        float p[4][4], ts[4];
#pragma unroll
        for (int n = 0; n < 4; ++n)
#pragma unroll
          for (int j = 0; j < 4; ++j) p[n][j] = __expf(sv[n][j] - nm[j]);
#pragma unroll
        for (int j = 0; j < 4; ++j) ts[j] = (p[0][j] + p[1][j]) + (p[2][j] + p[3][j]);
#pragma unroll
        for (int off = 1; off < 16; off <<= 1)
#pragma unroll
          for (int j = 0; j < 4; ++j) ts[j] += __shfl_xor(ts[j], off);
#pragma unroll
        for (int j = 0; j < 4; ++j) l_run[mh][j] = l_run[mh][j] * cr[j] + ts[j];
#pragma unroll
        for (int n = 0; n < 8; ++n)
#pragma unroll
          for (int j = 0; j < 4; ++j) acc[mh][n][j] *= cr[j];
#pragma unroll
        for (int n = 0; n < 4; ++n)
#pragma unroll
          for (int j = 0; j < 4; ++j)
            Ps[w][mh * 16 + lg * 4 + j][n * 16 + lr] = f2b(p[n][j]);
      }

      // ---- PV, V fragments shared across both m-halves
#pragma unroll
      for (int kstep = 0; kstep < 2; ++kstep) {
        bf16x8 pa0 = *(const bf16x8*)&Ps[w][lr][kstep * 32 + lg * 8];
        bf16x8 pa1 = *(const bf16x8*)&Ps[w][16 + lr][kstep * 32 + lg * 8];
#pragma unroll
        for (int n = 0; n < 8; ++n) {
          bf16x8 bv = *(const bf16x8*)&Vt[n * 16 + lr][kstep * 32 + lg * 8];
          acc[0][n] = __builtin_amdgcn_mfma_f32_16x16x32_bf16(pa0, bv, acc[0][n], 0, 0, 0);
          acc[1][n] = __builtin_amdgcn_mfma_f32_16x16x32_bf16(pa1, bv, acc[1][n], 0, 0, 0);
        }
      }
    }

    __syncthreads();                       // all waves done reading tile t
    if (t + 1 < ntiles) write_tile(P, Ks, Vt, tid);
    __syncthreads();                       // tile t+1 visible
  }

  // ---- epilogue
#pragma unroll
  for (int mh = 0; mh < 2; ++mh) {
    float inv[4];
#pragma unroll
    for (int j = 0; j < 4; ++j) inv[j] = 1.0f / l_run[mh][j];
    const int qrow = row0 + mh * 16 + lg * 4;
#pragma unroll
    for (int n = 0; n < 8; ++n)
#pragma unroll
      for (int j = 0; j < 4; ++j)
        out[((size_t)(bat * Sz + qrow + j) * Hz + h) * 128 + n * 16 + lr] = acc[mh][n][j] * inv[j];
  }
}

// ---------------------------------------------------------------- launch
extern "C" void kernel_launch(void* const* d_in, const int* in_sizes, int n_in,
                              void* d_out, int out_size, void* d_ws, size_t ws_size,
                              hipStream_t stream) {
  const float* q    = (const float*)d_in[0];
  const float* ckv  = (const float*)d_in[1];
  const float* rope = (const float*)d_in[2];
  const float* wup  = (const float*)d_in[3];
  float* out = (float*)d_out;

  unsigned short* ckvb = (unsigned short*)d_ws;
  unsigned short* wupb = ckvb + (size_t)4096 * RANKz;
  unsigned short* kvb  = wupb + (size_t)4096 * RANKz;
  unsigned short* ropeb = kvb + (size_t)4096 * 4096;

  const int nvec = 4096 * RANKz / 4;       // 524288 float4 per matrix
  const int nrope = 4096 * 64 / 4;         // 65536 float4
  cvt_bf16_kernel<<<(2 * nvec + nrope) / 256, 256, 0, stream>>>(ckv, ckvb, wup, wupb, rope, ropeb, nvec, nvec);

  dim3 gg(32, 32);
  gemm_kv_bf16<<<gg, 256, 0, stream>>>(ckvb, wupb, kvb);

  dim3 ga(8, 64);
  mla_attn_mfma<<<ga, 256, 0, stream>>>(q, kvb, ropeb, out);
}